// Round 1
// baseline (210.072 us; speedup 1.0000x reference)
//
#include <hip/hip_runtime.h>
#include <cmath>

#define NR 65536
#define DIM 512
#define KC 128

// ---------------------------------------------------------------------------
// Kernel A: segment sum. grid = (8 col-slices, nchunks row-chunks), 512 thr.
// Each block accumulates a [128][64] fp32 tile in LDS (ds_add_f32), then
// writes its deterministic partial to workspace (no global atomics).
// ---------------------------------------------------------------------------
__global__ __launch_bounds__(512) void vmf_segsum(
    const float* __restrict__ X, const int* __restrict__ y,
    float* __restrict__ partial, float* __restrict__ pcount,
    int rows_per_chunk)
{
    __shared__ float acc[KC * 64];
    __shared__ float cnt[KC];
    const int tid   = threadIdx.x;
    const int slice = blockIdx.x;           // 0..7 (64 columns each)
    const int chunk = blockIdx.y;
    const int d0    = slice * 64;
    for (int i = tid; i < KC * 64; i += 512) acc[i] = 0.f;
    if (slice == 0 && tid < KC) cnt[tid] = 0.f;
    __syncthreads();

    const int lane = tid & 63;
    const int w    = tid >> 6;              // 8 waves per block
    const int r0   = chunk * rows_per_chunk;
    int r1 = r0 + rows_per_chunk; if (r1 > NR) r1 = NR;
    const bool count_lane = (slice == 0) && (lane == 0);

    int row = r0 + w;
    // unroll by 8: 8 outstanding 256B loads per wave before LDS ops
    for (; row + 56 < r1; row += 64) {
        int   cc[8]; float vv[8];
        #pragma unroll
        for (int u = 0; u < 8; ++u) {
            int rw = row + 8 * u;
            cc[u] = y[rw];
            vv[u] = X[(size_t)rw * DIM + d0 + lane];
        }
        #pragma unroll
        for (int u = 0; u < 8; ++u) {
            unsafeAtomicAdd(&acc[cc[u] * 64 + lane], vv[u]);
            if (count_lane) unsafeAtomicAdd(&cnt[cc[u]], 1.f);
        }
    }
    for (; row < r1; row += 8) {
        int c = y[row];
        float v = X[(size_t)row * DIM + d0 + lane];
        unsafeAtomicAdd(&acc[c * 64 + lane], v);
        if (count_lane) unsafeAtomicAdd(&cnt[c], 1.f);
    }
    __syncthreads();

    for (int i = tid; i < KC * 64; i += 512) {
        int k = i >> 6, c = i & 63;
        partial[(size_t)(chunk * KC + k) * DIM + d0 + c] = acc[i];
    }
    if (slice == 0 && tid < KC) pcount[chunk * KC + tid] = cnt[tid];
}

// ---------------------------------------------------------------------------
// Kernel B: reduce partials -> r[K][D]; per-class norm, n, kappa, logk, ive.
// 128 blocks (one per class) x 256 threads, float2-vectorized.
// ---------------------------------------------------------------------------
__global__ __launch_bounds__(256) void vmf_reduce(
    const float* __restrict__ partial, const float* __restrict__ pcount,
    float* __restrict__ r, float* __restrict__ kappa, float* __restrict__ logk,
    float* __restrict__ bes, float* __restrict__ innorm, int nchunks)
{
    const int k = blockIdx.x, tid = threadIdx.x;
    float2 s = make_float2(0.f, 0.f);
    for (int c = 0; c < nchunks; ++c) {
        const float2* p = (const float2*)(partial + (size_t)(c * KC + k) * DIM);
        float2 v = p[tid];
        s.x += v.x; s.y += v.y;
    }
    ((float2*)(r + (size_t)k * DIM))[tid] = s;
    float ss = s.x * s.x + s.y * s.y;
    for (int off = 32; off; off >>= 1) ss += __shfl_down(ss, off);
    __shared__ float wsum[4];
    if ((tid & 63) == 0) wsum[tid >> 6] = ss;
    __syncthreads();
    if (tid == 0) {
        float tot  = wsum[0] + wsum[1] + wsum[2] + wsum[3];
        float norm = sqrtf(tot);
        float nk = 0.f;
        for (int c = 0; c < nchunks; ++c) nk += pcount[c * KC + k];
        float rb  = norm / nk;
        float kap = ((float)DIM * rb - rb * rb * rb) / (1.f - rb * rb);
        if (rb > 0.9f) kap = -0.4f + 1.39f * rb + 0.43f / (1.f - rb);
        kappa[k] = kap;
        logk[k]  = logf(kap);
        // _ive(d_star=255.5, kap) — A&S 9.7.7 uniform asymptotic, fp32
        const float v  = 255.5f;
        float zz = kap / v;
        float sq = sqrtf(1.f + zz * zz);
        float t  = 1.f / sq, t2 = t * t;
        float eta = sq + logf(zz / (1.f + sq));
        float u1 = (3.f * t - 5.f * t * t2) / 24.f;
        float u2 = (81.f * t2 - 462.f * t2 * t2 + 385.f * t2 * t2 * t2) / 1152.f;
        float u3 = (30375.f * t * t2 - 369603.f * t * t2 * t2
                    + 765765.f * t * t2 * t2 * t2
                    - 425425.f * t * t2 * t2 * t2 * t2) / 414720.f;
        float series = 1.f + u1 / v + u2 / (v * v) + u3 / (v * v * v);
        float ive = expf(v * eta - kap) * series
                    / (sqrtf(2.f * 3.14159265358979f * v) * sqrtf(sq));
        bes[k] = ive;
        innorm[k] = 1.f / norm;
    }
}

// ---------------------------------------------------------------------------
// Kernel C: block i computes kl[i][j]^2 for all j, reduces to rowsum[i].
// dots[i][j] = (r_i . r_j) * innorm_i * innorm_j  (mu never materialized).
// ---------------------------------------------------------------------------
__global__ __launch_bounds__(128) void vmf_gram(
    const float* __restrict__ r, const float* __restrict__ kappa,
    const float* __restrict__ logk, const float* __restrict__ bes,
    const float* __restrict__ innorm, float* __restrict__ rowsum)
{
    const int i = blockIdx.x, j = threadIdx.x;
    __shared__ float mui[DIM];
    const float inv_i = innorm[i];
    for (int d = j; d < DIM; d += 128) mui[d] = r[(size_t)i * DIM + d] * inv_i;
    __syncthreads();

    const float4* rj = (const float4*)(r + (size_t)j * DIM);
    float acc = 0.f;
    #pragma unroll 4
    for (int d4 = 0; d4 < DIM / 4; ++d4) {
        float4 v = rj[d4];
        acc += mui[d4 * 4 + 0] * v.x + mui[d4 * 4 + 1] * v.y
             + mui[d4 * 4 + 2] * v.z + mui[d4 * 4 + 3] * v.w;
    }
    const float dot = acc * innorm[j];
    const float dstar = 255.5f;
    float kl = dstar * (logk[j] - logk[i]) - kappa[i] + bes[i] - bes[j]
             + kappa[j] * dot;
    float v2 = kl * kl;
    for (int off = 32; off; off >>= 1) v2 += __shfl_down(v2, off);
    __shared__ float ws2[2];
    if ((j & 63) == 0) ws2[j >> 6] = v2;
    __syncthreads();
    if (j == 0) rowsum[i] = ws2[0] + ws2[1];
}

// ---------------------------------------------------------------------------
// Kernel D: sum 128 row sums -> out[0] = total / K^2
// ---------------------------------------------------------------------------
__global__ __launch_bounds__(128) void vmf_final(
    const float* __restrict__ rowsum, float* __restrict__ out)
{
    const int t = threadIdx.x;
    float v = rowsum[t];
    for (int off = 32; off; off >>= 1) v += __shfl_down(v, off);
    __shared__ float w[2];
    if ((t & 63) == 0) w[t >> 6] = v;
    __syncthreads();
    if (t == 0) out[0] = (w[0] + w[1]) / (float)(KC * KC);
}

extern "C" void kernel_launch(void* const* d_in, const int* in_sizes, int n_in,
                              void* d_out, int out_size, void* d_ws, size_t ws_size,
                              hipStream_t stream)
{
    const float* X = (const float*)d_in[0];
    const int*   y = (const int*)d_in[1];
    float* out = (float*)d_out;
    float* ws  = (float*)d_ws;

    // workspace layout (floats)
    float* r      = ws;                   // 65536
    float* kappa  = ws + 65536;           // 128
    float* logk   = ws + 65536 + 128;     // 128
    float* bes    = ws + 65536 + 256;     // 128
    float* innorm = ws + 65536 + 384;     // 128
    float* rowsum = ws + 65536 + 512;     // 128
    float* pcount = ws + 66176;           // up to 32*128 = 4096
    float* partial = ws + 131072;         // nchunks * 128 * 512

    size_t avail = ws_size / 4;
    int nchunks = 32;
    if (avail < (size_t)131072 + (size_t)32 * KC * DIM) {
        long c = (long)((avail > 131072 ? avail - 131072 : 0) / (KC * DIM));
        if (c < 1) c = 1;
        if (c > 32) c = 32;
        nchunks = (int)c;
    }
    int rows_per_chunk = (NR + nchunks - 1) / nchunks;

    dim3 gA(8, nchunks);
    vmf_segsum<<<gA, 512, 0, stream>>>(X, y, partial, pcount, rows_per_chunk);
    vmf_reduce<<<KC, 256, 0, stream>>>(partial, pcount, r, kappa, logk, bes,
                                       innorm, nchunks);
    vmf_gram<<<KC, 128, 0, stream>>>(r, kappa, logk, bes, innorm, rowsum);
    vmf_final<<<1, 128, 0, stream>>>(rowsum, out);
}

// Round 2
// 207.787 us; speedup vs baseline: 1.0110x; 1.0110x over previous
//
#include <hip/hip_runtime.h>
#include <cmath>

#define NR 65536
#define DIM 512
#define KC 128
#define SLICES 4
#define SCOLS 128   // columns per slice

// ---------------------------------------------------------------------------
// Kernel 0: class counts. 64 blocks x 256 threads, int4 loads, LDS histogram,
// one global int atomicAdd per class per block (exact -> deterministic).
// ---------------------------------------------------------------------------
__global__ __launch_bounds__(256) void vmf_count(
    const int* __restrict__ y, int* __restrict__ ncount)
{
    __shared__ int cnt[KC];
    const int t = threadIdx.x;
    if (t < KC) cnt[t] = 0;
    __syncthreads();
    const int4 v = ((const int4*)y)[blockIdx.x * 256 + t];
    atomicAdd(&cnt[v.x], 1);
    atomicAdd(&cnt[v.y], 1);
    atomicAdd(&cnt[v.z], 1);
    atomicAdd(&cnt[v.w], 1);
    __syncthreads();
    if (t < KC) atomicAdd(&ncount[t], cnt[t]);
}

// ---------------------------------------------------------------------------
// Kernel A: segment sum. grid = (4 col-slices, nchunks), 512 threads.
// Macro-tile = 16 rows per wave: 1 lane-indexed y load (classes via __shfl),
// 8 float4 X loads (2 rows x 512B each) kept in flight, then 32 swizzled
// conflict-free ds_add_f32. LDS tile [128][128] fp32 = 64 KB,
// layout acc[c*128 + (col&3)*32 + (col>>2)] -> each atomic quad hits
// banks 0..31 with exactly 2 lanes/bank.
// ---------------------------------------------------------------------------
__global__ __launch_bounds__(512, 2) void vmf_segsum(
    const float* __restrict__ X, const int* __restrict__ y,
    float* __restrict__ partial, int rows_per_chunk)
{
    __shared__ float acc[KC * SCOLS];          // 64 KB
    const int tid   = threadIdx.x;
    const int lane  = tid & 63;
    const int w     = tid >> 6;                // 8 waves
    const int slice = blockIdx.x;
    const int chunk = blockIdx.y;
    const int d0    = slice * SCOLS;

    for (int i = tid; i < KC * SCOLS / 4; i += 512)
        ((float4*)acc)[i] = make_float4(0.f, 0.f, 0.f, 0.f);
    __syncthreads();

    const int cl = lane & 31;                  // column-quad index within row
    const int g  = lane >> 5;                  // row sub-group (0/1)
    const int r0 = chunk * rows_per_chunk;
    const int r1 = r0 + rows_per_chunk;        // rows_per_chunk multiple of 16

    for (int rb = r0 + w * 16; rb < r1; rb += 128) {
        const int yv = y[rb + (lane & 15)];    // 16 classes, lane-resident
        float4 xv[8];
        #pragma unroll
        for (int gg = 0; gg < 8; ++gg) {
            const int row = rb + 2 * gg + g;
            xv[gg] = *(const float4*)(X + (size_t)row * DIM + d0 + cl * 4);
        }
        #pragma unroll
        for (int gg = 0; gg < 8; ++gg) {
            const int c = __shfl(yv, 2 * gg + g);
            float* a = &acc[c * SCOLS + cl];
            unsafeAtomicAdd(a +  0, xv[gg].x);
            unsafeAtomicAdd(a + 32, xv[gg].y);
            unsafeAtomicAdd(a + 64, xv[gg].z);
            unsafeAtomicAdd(a + 96, xv[gg].w);
        }
    }
    __syncthreads();

    for (int i = tid; i < KC * SCOLS; i += 512) {
        const int c = i >> 7, col = i & 127;
        partial[(size_t)(chunk * KC + c) * DIM + d0 + col] =
            acc[c * SCOLS + ((col & 3) << 5) + (col >> 2)];
    }
}

// ---------------------------------------------------------------------------
// Kernel B: reduce partials -> r[K][D]; per-class norm, kappa, logk, ive.
// 128 blocks (one per class) x 512 threads; thread (cg,q) sums chunk-stripe
// cg over float4 column q -> 16 independent float4 loads each.
// ---------------------------------------------------------------------------
__global__ __launch_bounds__(512) void vmf_reduce(
    const float* __restrict__ partial, const int* __restrict__ ncount,
    float* __restrict__ r, float* __restrict__ kappa, float* __restrict__ logk,
    float* __restrict__ bes, float* __restrict__ innorm, int nchunks)
{
    const int k = blockIdx.x, t = threadIdx.x;
    const int q  = t & 127;                    // float4 column
    const int cg = t >> 7;                     // chunk stripe 0..3
    float4 s = make_float4(0.f, 0.f, 0.f, 0.f);
    for (int c = cg; c < nchunks; c += 4) {
        const float4 v = ((const float4*)(partial + (size_t)(c * KC + k) * DIM))[q];
        s.x += v.x; s.y += v.y; s.z += v.z; s.w += v.w;
    }
    __shared__ float4 red[512];                // 8 KB
    red[t] = s;
    __syncthreads();

    float ss = 0.f;
    if (t < 128) {
        const float4 a = red[t], b = red[t + 128], c2 = red[t + 256], d2 = red[t + 384];
        float4 tot;
        tot.x = a.x + b.x + c2.x + d2.x;
        tot.y = a.y + b.y + c2.y + d2.y;
        tot.z = a.z + b.z + c2.z + d2.z;
        tot.w = a.w + b.w + c2.w + d2.w;
        ((float4*)(r + (size_t)k * DIM))[t] = tot;
        ss = tot.x * tot.x + tot.y * tot.y + tot.z * tot.z + tot.w * tot.w;
    }
    for (int off = 32; off; off >>= 1) ss += __shfl_down(ss, off);
    __shared__ float wsum[8];
    if ((t & 63) == 0) wsum[t >> 6] = ss;
    __syncthreads();
    if (t == 0) {
        const float tot  = wsum[0] + wsum[1];
        const float norm = sqrtf(tot);
        const float nk   = (float)ncount[k];
        const float rb   = norm / nk;
        float kap = ((float)DIM * rb - rb * rb * rb) / (1.f - rb * rb);
        if (rb > 0.9f) kap = -0.4f + 1.39f * rb + 0.43f / (1.f - rb);
        kappa[k] = kap;
        logk[k]  = logf(kap);
        const float v  = 255.5f;
        const float zz = kap / v;
        const float sq = sqrtf(1.f + zz * zz);
        const float tt = 1.f / sq, t2 = tt * tt;
        const float eta = sq + logf(zz / (1.f + sq));
        const float u1 = (3.f * tt - 5.f * tt * t2) / 24.f;
        const float u2 = (81.f * t2 - 462.f * t2 * t2 + 385.f * t2 * t2 * t2) / 1152.f;
        const float u3 = (30375.f * tt * t2 - 369603.f * tt * t2 * t2
                    + 765765.f * tt * t2 * t2 * t2
                    - 425425.f * tt * t2 * t2 * t2 * t2) / 414720.f;
        const float series = 1.f + u1 / v + u2 / (v * v) + u3 / (v * v * v);
        const float ive = expf(v * eta - kap) * series
                    / (sqrtf(2.f * 3.14159265358979f * v) * sqrtf(sq));
        bes[k] = ive;
        innorm[k] = 1.f / norm;
    }
}

// ---------------------------------------------------------------------------
// Kernel C: block i computes kl[i][j]^2 for all j, reduces to rowsum[i].
// ---------------------------------------------------------------------------
__global__ __launch_bounds__(128) void vmf_gram(
    const float* __restrict__ r, const float* __restrict__ kappa,
    const float* __restrict__ logk, const float* __restrict__ bes,
    const float* __restrict__ innorm, float* __restrict__ rowsum)
{
    const int i = blockIdx.x, j = threadIdx.x;
    __shared__ float mui[DIM];
    const float inv_i = innorm[i];
    for (int d = j; d < DIM; d += 128) mui[d] = r[(size_t)i * DIM + d] * inv_i;
    __syncthreads();

    const float4* rj = (const float4*)(r + (size_t)j * DIM);
    float acc = 0.f;
    #pragma unroll 4
    for (int d4 = 0; d4 < DIM / 4; ++d4) {
        float4 v = rj[d4];
        acc += mui[d4 * 4 + 0] * v.x + mui[d4 * 4 + 1] * v.y
             + mui[d4 * 4 + 2] * v.z + mui[d4 * 4 + 3] * v.w;
    }
    const float dot = acc * innorm[j];
    const float dstar = 255.5f;
    float kl = dstar * (logk[j] - logk[i]) - kappa[i] + bes[i] - bes[j]
             + kappa[j] * dot;
    float v2 = kl * kl;
    for (int off = 32; off; off >>= 1) v2 += __shfl_down(v2, off);
    __shared__ float ws2[2];
    if ((j & 63) == 0) ws2[j >> 6] = v2;
    __syncthreads();
    if (j == 0) rowsum[i] = ws2[0] + ws2[1];
}

// ---------------------------------------------------------------------------
// Kernel D: sum 128 row sums -> out[0] = total / K^2
// ---------------------------------------------------------------------------
__global__ __launch_bounds__(128) void vmf_final(
    const float* __restrict__ rowsum, float* __restrict__ out)
{
    const int t = threadIdx.x;
    float v = rowsum[t];
    for (int off = 32; off; off >>= 1) v += __shfl_down(v, off);
    __shared__ float w[2];
    if ((t & 63) == 0) w[t >> 6] = v;
    __syncthreads();
    if (t == 0) out[0] = (w[0] + w[1]) / (float)(KC * KC);
}

extern "C" void kernel_launch(void* const* d_in, const int* in_sizes, int n_in,
                              void* d_out, int out_size, void* d_ws, size_t ws_size,
                              hipStream_t stream)
{
    const float* X = (const float*)d_in[0];
    const int*   y = (const int*)d_in[1];
    float* out = (float*)d_out;
    float* ws  = (float*)d_ws;

    // workspace layout (float units)
    float* r      = ws;                    // 65536
    float* kappa  = ws + 65536;            // 128
    float* logk   = ws + 65536 + 128;
    float* bes    = ws + 65536 + 256;
    float* innorm = ws + 65536 + 384;
    float* rowsum = ws + 65536 + 512;
    int*   ncount = (int*)(ws + 65536 + 640);   // 128 ints
    float* partial = ws + 66560;           // nchunks * KC * DIM

    const size_t avail = ws_size / 4;
    int nchunks = 64;
    while (nchunks > 1 &&
           (size_t)66560 + (size_t)nchunks * KC * DIM > avail)
        nchunks >>= 1;
    const int rows_per_chunk = NR / nchunks;   // multiple of 16 (pow2 chunks)

    hipMemsetAsync(ncount, 0, KC * sizeof(int), stream);
    vmf_count<<<NR / 4 / 256, 256, 0, stream>>>(y, ncount);
    dim3 gA(SLICES, nchunks);
    vmf_segsum<<<gA, 512, 0, stream>>>(X, y, partial, rows_per_chunk);
    vmf_reduce<<<KC, 512, 0, stream>>>(partial, ncount, r, kappa, logk, bes,
                                       innorm, nchunks);
    vmf_gram<<<KC, 128, 0, stream>>>(r, kappa, logk, bes, innorm, rowsum);
    vmf_final<<<1, 128, 0, stream>>>(rowsum, out);
}